// Round 8
// baseline (971.321 us; speedup 1.0000x reference)
//
#include <hip/hip_runtime.h>
#include <math.h>
#include <stdint.h>
#include <stddef.h>

typedef short short8 __attribute__((ext_vector_type(8)));   // 8 x bf16 fragment
typedef float f32x4 __attribute__((ext_vector_type(4)));

#define NKT 24           // 768 / 32 K-tiles
#define ROWPB 80         // LDS tile row stride: 64 B real (32 bf16) + 16 B pad
#define NWG 1452         // 484 mt * 3 nt

// DCT basis (P=3): rows {CA,CA,CA},{CB,0,-CB},{CC,CD,CC}
#define CA 0.57735026918962576f
#define CB 0.70710678118654752f
#define CC 0.40824829046386302f
#define CD -0.81649658092772603f

// double-buffered GEMM tiles (64000 B); epilogue [72][256] f32 = 73728 B
#define LDS_A0 0u
#define LDS_A1 11520u
#define LDS_B0 23040u
#define LDS_B1 43520u
#define LDS_TOTAL 73728

// f32 -> bf16 round-to-nearest-even
static __device__ __forceinline__ unsigned short f2bf(float x) {
  union { float f; unsigned u; } v; v.f = x;
  unsigned r = v.u + 0x7fffu + ((v.u >> 16) & 1u);
  return (unsigned short)(r >> 16);
}

// ---------------------------------------------------------------------------
// R8: occupancy attack. Same 144x256 tile and verified math, but 1024 threads
//   (16 waves): per-wave C-strip 144x16 -> acc[9] = 36 f32/lane (was 72).
//   Unified regs/wave ~150 <= 256 cap -> 2 blocks/CU co-resident; the other
//   block's MFMA fills this block's stage/vmcnt/barrier stalls (m114).
//   - A-staging: wave = window; both 32-lane halves compute the DCT, rows
//     split 4/5 between halves for the LDS writes.
//   - B-staging: thread=(row bn=tid>>2, quarter): 8 f32 -> one 16 B ds_write.
//   - dbuf one-barrier K-loop kept; XCD swizzle dropped (isolating R7's -11%).
//   - NT epilogue stores kept (R5-proven).
// ---------------------------------------------------------------------------
__global__ __launch_bounds__(1024, 8) void fused_kernel(
    const float* __restrict__ f, const float* __restrict__ W1,
    const float* __restrict__ b1, float* __restrict__ out) {
  __shared__ alignas(16) unsigned char smem[LDS_TOTAL];

  const int bid = blockIdx.x;
  const int mt = bid / 3;
  const int nt = bid - mt * 3;
  const int n0 = nt * 256;
  const int tid = threadIdx.x;
  const int wv = tid >> 6;           // 0..15
  const int lane = tid & 63;
  const int lrow = lane & 15;        // C col within 16-col fragment
  const int kgrp = lane >> 4;        // 0..3

  const float Cm[3][3] = {{CA, CA, CA}, {CB, 0.f, -CB}, {CC, CD, CC}};

  // ---- A-staging geometry: wave wv stages window wv; ak = lane&31 ----
  const int aw = wv;
  const int ak = tid & 31;
  const int h2 = (tid >> 5) & 1;                 // rows 0..3 vs 4..8
  const int gwin = mt * 16 + aw;                 // 0..7743
  const int ab2 = gwin / 484;                    // image 0..15
  const int arem = gwin - ab2 * 484;
  const int abh = arem / 22;
  const int abw = arem - abh * 22;
  const float* fp[9];
#pragma unroll
  for (int p = 0; p < 3; ++p) {
    int h = abh * 3 + p; h = h > 63 ? 63 : h;    // edge padding == index clamp
#pragma unroll
    for (int q = 0; q < 3; ++q) {
      int w = abw * 3 + q; w = w > 63 ? 63 : w;
      fp[p * 3 + q] = f + ((((size_t)ab2 * 64 + h) * 64 + w) * 768 + ak);
    }
  }
  const unsigned abase0 = (unsigned)(aw * 9) * ROWPB + (unsigned)ak * 2;

  // ---- B-staging geometry: thread = (row bn=tid>>2, quarter qu=tid&3) ----
  const int bn = tid >> 2;           // 0..255
  const int qu = tid & 3;            // 0..3  (8 floats each)
  const float* gW = W1 + (size_t)(n0 + bn) * 768 + qu * 8;
  const unsigned bwr = (unsigned)bn * ROWPB + (unsigned)qu * 16;

  f32x4 acc[9];
#pragma unroll
  for (int i = 0; i < 9; ++i) acc[i] = (f32x4){0.f, 0.f, 0.f, 0.f};

  float xr[9];
  f32x4 wr[2];
  auto loadF = [&](int kt) {
    const int off = kt * 32;
#pragma unroll
    for (int i = 0; i < 9; ++i) xr[i] = fp[i][off];
  };
  auto loadB = [&](int kt) {
    const float* p = gW + kt * 32;
    wr[0] = *(const f32x4*)(p);
    wr[1] = *(const f32x4*)(p + 4);
  };
  auto dctWriteA = [&](unsigned abuf) {
    float s1[3][3];
#pragma unroll
    for (int p = 0; p < 3; ++p)
#pragma unroll
      for (int c = 0; c < 3; ++c)
        s1[p][c] = Cm[c][0] * xr[p * 3] + Cm[c][1] * xr[p * 3 + 1] + Cm[c][2] * xr[p * 3 + 2];
#pragma unroll
    for (int a = 0; a < 3; ++a)
#pragma unroll
      for (int c = 0; c < 3; ++c) {
        const int r = a * 3 + c;
        if ((r < 4) ? (h2 == 0) : (h2 == 1)) {   // split 9 row-writes 4/5
          float t = Cm[a][0] * s1[0][c] + Cm[a][1] * s1[1][c] + Cm[a][2] * s1[2][c];
          *(unsigned short*)(smem + abuf + abase0 + (unsigned)r * ROWPB) = f2bf(t);
        }
      }
  };
  auto writeB = [&](unsigned bbuf) {
    short8 s0;
#pragma unroll
    for (int i = 0; i < 4; ++i) {
      s0[i]     = (short)f2bf(wr[0][i]);
      s0[i + 4] = (short)f2bf(wr[1][i]);
    }
    *(short8*)(smem + bbuf + bwr) = s0;
  };

  const unsigned aoff = (unsigned)lrow * ROWPB + (unsigned)kgrp * 16;
  const unsigned boff = (unsigned)(wv * 16 + lrow) * ROWPB + (unsigned)kgrp * 16;

  // ---- prologue: stage tile 0 into buffer 0 ----
  loadF(0);
  loadB(0);
  dctWriteA(LDS_A0);
  writeB(LDS_B0);
  __syncthreads();

  // ---- main loop: dbuf, ONE barrier per K-step ----
  for (int kt = 0; kt < NKT; ++kt) {
    const int buf = kt & 1;
    if (kt + 1 < NKT) {            // issue next tile's global loads first
      loadF(kt + 1);
      loadB(kt + 1);
    }
    const unsigned ab = buf ? LDS_A1 : LDS_A0;
    const unsigned bb = buf ? LDS_B1 : LDS_B0;
    short8 bf0 = *(const short8*)(smem + bb + boff);
#pragma unroll
    for (int rf = 0; rf < 9; ++rf) {
      short8 af = *(const short8*)(smem + ab + aoff + (unsigned)rf * (16u * ROWPB));
      acc[rf] = __builtin_amdgcn_mfma_f32_16x16x32_bf16(af, bf0, acc[rf], 0, 0, 0);
    }
    if (kt + 1 < NKT) {            // convert + stage kt+1 into the other buffer
      dctWriteA(buf ? LDS_A0 : LDS_A1);
      writeB(buf ? LDS_B0 : LDS_B1);
    }
    __syncthreads();               // writes visible; all reads of 'buf' done
  }

  // ---- epilogue: two window-half passes over a shared [72][256] tile ----
  float* ep2 = (float*)smem;
  const int colE = wv * 16 + lrow;
  const float bias = b1[n0 + colE];

#pragma unroll 1
  for (int hs = 0; hs < 2; ++hs) {
    __syncthreads();               // previous readers of smem are done
    // (1) GELU -> ep2 for M-rows [hs*72, hs*72+72), this wave's 16 cols
#pragma unroll
    for (int rf = 0; rf < 9; ++rf) {
#pragma unroll
      for (int j = 0; j < 4; ++j) {
        const int r = rf * 16 + kgrp * 4 + j;   // C/D: row=(lane>>4)*4+reg
        const int lr = r - hs * 72;
        if (lr >= 0 && lr < 72) {
          float v = acc[rf][j] + bias;
          float g = 0.5f * v * (1.0f + erff(v * 0.70710678118654752f));
          ep2[lr * 256 + colE] = g;
        }
      }
    }
    __syncthreads();
    // (2) wave-pair per window: wave wv does 2 of the 4 64-col chunks of
    //     window hs*8 + (wv>>1); 256 B contiguous NT stores
    const int wl = wv >> 1;               // window within half (0..7)
    const int gw = mt * 16 + hs * 8 + wl;
    const int ib = gw / 484;
    const int rem = gw - ib * 484;
    const int bh = rem / 22;
    const int bw = rem - bh * 22;
    const float* epw = ep2 + wl * 9 * 256;
#pragma unroll
    for (int cc = 0; cc < 2; ++cc) {
      const int col = ((wv & 1) * 2 + cc) * 64 + lane;
      float y[3][3];
#pragma unroll
      for (int a = 0; a < 3; ++a)
#pragma unroll
        for (int c = 0; c < 3; ++c)
          y[a][c] = epw[(a * 3 + c) * 256 + col];
      float vt[3][3];                 // vt[a][q] = sum_c y[a][c] * Cm[c][q]
#pragma unroll
      for (int a = 0; a < 3; ++a)
#pragma unroll
        for (int q = 0; q < 3; ++q)
          vt[a][q] = y[a][0] * Cm[0][q] + y[a][1] * Cm[1][q] + y[a][2] * Cm[2][q];
#pragma unroll
      for (int p = 0; p < 3; ++p) {
        const int h = bh * 3 + p;
        if (h >= 64) continue;        // crop (uniform per wave)
#pragma unroll
        for (int q = 0; q < 3; ++q) {
          const int ww = bw * 3 + q;
          if (ww >= 64) continue;     // crop (uniform per wave)
          const float o = Cm[0][p] * vt[0][q] + Cm[1][p] * vt[1][q] + Cm[2][p] * vt[2][q];
          __builtin_nontemporal_store(
              o, out + ((((size_t)ib * 64 + h) * 64 + ww) * 768 + n0 + col));
        }
      }
    }
  }
}

// ---------------------------------------------------------------------------
extern "C" void kernel_launch(void* const* d_in, const int* in_sizes, int n_in,
                              void* d_out, int out_size, void* d_ws, size_t ws_size,
                              hipStream_t stream) {
  const float* f  = (const float*)d_in[0];
  const float* W1 = (const float*)d_in[1];
  const float* b1 = (const float*)d_in[2];
  float* out = (float*)d_out;
  (void)d_ws; (void)ws_size;   // zero-workspace design

  fused_kernel<<<dim3(NWG), dim3(1024), 0, stream>>>(f, W1, b1, out);
}

// Round 9
// 243.148 us; speedup vs baseline: 3.9948x; 3.9948x over previous
//
#include <hip/hip_runtime.h>
#include <math.h>
#include <stdint.h>
#include <stddef.h>

typedef short short8 __attribute__((ext_vector_type(8)));   // 8 x bf16 fragment
typedef float f32x4 __attribute__((ext_vector_type(4)));

// DCT basis (P=3): rows {CA,CA,CA},{CB,0,-CB},{CC,CD,CC}
#define CA 0.57735026918962576f
#define CB 0.70710678118654752f
#define CC 0.40824829046386302f
#define CD -0.81649658092772603f

#define NKT 24            // K-tiles of 32
#define KTL 4             // K-tiles per staging group
#define NG 6              // staging groups
#define NWIN 7744
#define NBLK 1549         // ceil(7744 / 5)
#define AROWB 80          // A-tile LDS row: 64 B real + 16 B pad (2-way banks)
#define ABUFB (KTL * 48 * AROWB)       // 15360 B per A buffer
#define LDS_TOTAL 147456               // epilogue: 12 waves * [48][64] f32
#define W1H_BYTES (24ull * 768 * 32 * 2)   // 1179648

static __device__ __forceinline__ unsigned short f2bf(float x) {
  union { float f; unsigned u; } v; v.f = x;
  unsigned r = v.u + 0x7fffu + ((v.u >> 16) & 1u);
  return (unsigned short)(r >> 16);
}

// ---------------------------------------------------------------------------
// Kernel 0: W1 f32 [o][i] -> bf16 packed [kt][n][32] (64 B rows, no pad).
// 18432 threads; writes coalesced (64 B/lane-group contiguous in n).
// ---------------------------------------------------------------------------
__global__ __launch_bounds__(256) void w1conv(const float* __restrict__ W1,
                                              unsigned short* __restrict__ W1h) {
  const int id = blockIdx.x * 256 + threadIdx.x;   // 24*768
  const int kt = id / 768;
  const int n = id - kt * 768;
  const float* src = W1 + (size_t)n * 768 + kt * 32;
  unsigned short* dst = W1h + ((size_t)kt * 768 + n) * 32;
#pragma unroll
  for (int i = 0; i < 4; ++i) {
    f32x4 v0 = *(const f32x4*)(src + i * 8);
    f32x4 v1 = *(const f32x4*)(src + i * 8 + 4);
    short8 s;
#pragma unroll
    for (int j = 0; j < 4; ++j) {
      s[j] = (short)f2bf(v0[j]);
      s[j + 4] = (short)f2bf(v1[j]);
    }
    *(short8*)(dst + i * 8) = s;
  }
}

// ---------------------------------------------------------------------------
// Main kernel: block = 5 windows (45 rows, MFMA-padded to 48) x ALL 768 cols.
//   768 threads / 12 waves; wave wv owns cols [wv*64, wv*64+64) -> acc 48 f32.
//   A: on-the-fly DCT staged in groups of 4 K-tiles -> only 6 barrier phases,
//      DCT computed ONCE per element (R5 did it 3x across nt-blocks).
//   B: global->register short8 fragments from W1h (L2-resident), 2-deep
//      pipelined; never in LDS. USE_WS=false falls back to f32 W1 + convert.
//   Rows 45..47 of each A-tile are never written; their acc rows are never
//   stored (MFMA D rows are independent), so garbage there is harmless.
//   Epilogue: per-wave [48][64] f32 scratch; wave holds complete windows for
//   its 64 cols -> IDCT + 256 B line-aligned NT stores, no cross-wave pass.
// ---------------------------------------------------------------------------
template <bool USE_WS>
__global__ __launch_bounds__(768, 3) void fused_kernel(
    const float* __restrict__ f, const float* __restrict__ W1,
    const unsigned short* __restrict__ W1h, const float* __restrict__ b1,
    float* __restrict__ out) {
  __shared__ alignas(16) unsigned char smem[LDS_TOTAL];

  const int mblk = blockIdx.x;
  const int tid = threadIdx.x;
  const int wv = tid >> 6;           // 0..11
  const int lane = tid & 63;
  const int lrow = lane & 15;
  const int kgrp = lane >> 4;        // 0..3

  // ---- staging unit: (window sw, k-tile sktl, feature sk); 640 active ----
  const int sk = tid & 31;
  const int sktl = (tid >> 5) & 3;
  const int sw = tid >> 7;           // 0..5 (5 -> inactive)
  const bool sact = (tid < 640);

  int sgw = mblk * 5 + sw; if (sgw > NWIN - 1) sgw = NWIN - 1;
  const int sib = sgw / 484;
  const int srem = sgw - sib * 484;
  const int sbh = srem / 22;
  const int sbw = srem - sbh * 22;
  const float* fbase = f + (size_t)sib * 64 * 64 * 768 + sk;
  int ho[3], wo[3];
#pragma unroll
  for (int p = 0; p < 3; ++p) {
    int h = sbh * 3 + p; h = h > 63 ? 63 : h;   // edge pad == clamp
    ho[p] = h * 64 * 768;
    int w = sbw * 3 + p; w = w > 63 ? 63 : w;
    wo[p] = w * 768;
  }
  const unsigned awr = (unsigned)(sktl * 48 + sw * 9) * AROWB + (unsigned)sk * 2;

  // ---- B fragment base (this wave's cols, this lane's 8-k slice) ----
  const unsigned short* pbW = W1h + ((size_t)(wv * 64 + lrow)) * 32 + kgrp * 8;
  const float* pbF = W1 + ((size_t)(wv * 64 + lrow)) * 768 + kgrp * 8;

  f32x4 acc[12];                     // [rf*4 + cf]
#pragma unroll
  for (int i = 0; i < 12; ++i) acc[i] = (f32x4){0.f, 0.f, 0.f, 0.f};

  float xr[9];
  auto loadF = [&](int g) {
    const int fo = g * 128 + sktl * 32;
#pragma unroll
    for (int p = 0; p < 3; ++p)
#pragma unroll
      for (int q = 0; q < 3; ++q)
        xr[p * 3 + q] = fbase[ho[p] + wo[q] + fo];
  };
  auto dctWrite = [&](unsigned abuf) {
    float s[3][3];
#pragma unroll
    for (int p = 0; p < 3; ++p) {
      const float t = xr[p * 3] + xr[p * 3 + 2];
      s[p][0] = CA * (t + xr[p * 3 + 1]);
      s[p][1] = CB * (xr[p * 3] - xr[p * 3 + 2]);
      s[p][2] = CC * t + CD * xr[p * 3 + 1];
    }
#pragma unroll
    for (int c = 0; c < 3; ++c) {
      const float t = s[0][c] + s[2][c];
      const float y0 = CA * (t + s[1][c]);
      const float y1 = CB * (s[0][c] - s[2][c]);
      const float y2 = CC * t + CD * s[1][c];
      *(unsigned short*)(smem + abuf + awr + (unsigned)c * AROWB) = f2bf(y0);
      *(unsigned short*)(smem + abuf + awr + (unsigned)(3 + c) * AROWB) = f2bf(y1);
      *(unsigned short*)(smem + abuf + awr + (unsigned)(6 + c) * AROWB) = f2bf(y2);
    }
  };

  short8 ba0, ba1, ba2, ba3;
  auto loadB = [&](int kt, short8& b0, short8& b1v, short8& b2, short8& b3) {
    if (USE_WS) {
      b0 = *(const short8*)(pbW + ((size_t)kt * 768 + 0) * 32);
      b1v = *(const short8*)(pbW + ((size_t)kt * 768 + 16) * 32);
      b2 = *(const short8*)(pbW + ((size_t)kt * 768 + 32) * 32);
      b3 = *(const short8*)(pbW + ((size_t)kt * 768 + 48) * 32);
    } else {
#pragma unroll
      for (int cf = 0; cf < 4; ++cf) {
        const float* p = pbF + (size_t)(cf * 16) * 768 + kt * 32;
        f32x4 v0 = *(const f32x4*)(p);
        f32x4 v1 = *(const f32x4*)(p + 4);
        short8 s;
#pragma unroll
        for (int j = 0; j < 4; ++j) {
          s[j] = (short)f2bf(v0[j]);
          s[j + 4] = (short)f2bf(v1[j]);
        }
        if (cf == 0) b0 = s; else if (cf == 1) b1v = s;
        else if (cf == 2) b2 = s; else b3 = s;
      }
    }
  };

  // ---- prologue: stage group 0 into buffer 0 ----
  if (sact) { loadF(0); dctWrite(0); }
  loadB(0, ba0, ba1, ba2, ba3);
  __syncthreads();

  // ---- main loop: 6 groups, ONE barrier each ----
#pragma unroll 1
  for (int g = 0; g < NG; ++g) {
    const unsigned abuf = (g & 1) ? ABUFB : 0u;
    if (g + 1 < NG && sact) loadF(g + 1);   // next group's f, early issue
#pragma unroll
    for (int ktl = 0; ktl < KTL; ++ktl) {
      short8 bb0, bb1, bb2, bb3;
      const int nkt = g * 4 + ktl + 1;
      if (nkt < NKT) loadB(nkt, bb0, bb1, bb2, bb3);   // 2-deep B pipeline
      const unsigned ab = abuf + (unsigned)(ktl * 48) * AROWB + (unsigned)kgrp * 16;
      short8 af0 = *(const short8*)(smem + ab + (unsigned)(0 * 16 + lrow) * AROWB);
      short8 af1 = *(const short8*)(smem + ab + (unsigned)(1 * 16 + lrow) * AROWB);
      short8 af2 = *(const short8*)(smem + ab + (unsigned)(2 * 16 + lrow) * AROWB);
      acc[0] = __builtin_amdgcn_mfma_f32_16x16x32_bf16(af0, ba0, acc[0], 0, 0, 0);
      acc[1] = __builtin_amdgcn_mfma_f32_16x16x32_bf16(af0, ba1, acc[1], 0, 0, 0);
      acc[2] = __builtin_amdgcn_mfma_f32_16x16x32_bf16(af0, ba2, acc[2], 0, 0, 0);
      acc[3] = __builtin_amdgcn_mfma_f32_16x16x32_bf16(af0, ba3, acc[3], 0, 0, 0);
      acc[4] = __builtin_amdgcn_mfma_f32_16x16x32_bf16(af1, ba0, acc[4], 0, 0, 0);
      acc[5] = __builtin_amdgcn_mfma_f32_16x16x32_bf16(af1, ba1, acc[5], 0, 0, 0);
      acc[6] = __builtin_amdgcn_mfma_f32_16x16x32_bf16(af1, ba2, acc[6], 0, 0, 0);
      acc[7] = __builtin_amdgcn_mfma_f32_16x16x32_bf16(af1, ba3, acc[7], 0, 0, 0);
      acc[8] = __builtin_amdgcn_mfma_f32_16x16x32_bf16(af2, ba0, acc[8], 0, 0, 0);
      acc[9] = __builtin_amdgcn_mfma_f32_16x16x32_bf16(af2, ba1, acc[9], 0, 0, 0);
      acc[10] = __builtin_amdgcn_mfma_f32_16x16x32_bf16(af2, ba2, acc[10], 0, 0, 0);
      acc[11] = __builtin_amdgcn_mfma_f32_16x16x32_bf16(af2, ba3, acc[11], 0, 0, 0);
      if (nkt < NKT) { ba0 = bb0; ba1 = bb1; ba2 = bb2; ba3 = bb3; }
    }
    if (g + 1 < NG && sact) dctWrite(abuf ^ ABUFB);   // stage next group
    __syncthreads();
  }

  // ---- epilogue: per-wave [48][64] scratch; GELU -> IDCT -> NT stores ----
  float* ep = (float*)(smem + wv * 12288);
  float bias[4];
#pragma unroll
  for (int cf = 0; cf < 4; ++cf) bias[cf] = b1[wv * 64 + cf * 16 + lrow];

#pragma unroll
  for (int rf = 0; rf < 3; ++rf)
#pragma unroll
    for (int cf = 0; cf < 4; ++cf)
#pragma unroll
      for (int j = 0; j < 4; ++j) {
        const int r = rf * 16 + kgrp * 4 + j;   // C/D: row=(lane>>4)*4+reg
        const float v = acc[rf * 4 + cf][j] + bias[cf];
        const float gl = 0.5f * v * (1.0f + erff(v * 0.70710678118654752f));
        ep[r * 64 + cf * 16 + lrow] = gl;
      }
  __syncthreads();   // also orders same-wave LDS RAW below

  const float Cm[3][3] = {{CA, CA, CA}, {CB, 0.f, -CB}, {CC, CD, CC}};
#pragma unroll 1
  for (int w = 0; w < 5; ++w) {
    const int gw = mblk * 5 + w;
    if (gw >= NWIN) break;                 // uniform per block
    const int ib = gw / 484;
    const int rem = gw - ib * 484;
    const int bh = rem / 22;
    const int bw = rem - bh * 22;
    float y[3][3];
#pragma unroll
    for (int a = 0; a < 3; ++a)
#pragma unroll
      for (int c = 0; c < 3; ++c)
        y[a][c] = ep[(w * 9 + a * 3 + c) * 64 + lane];
    float vt[3][3];                        // vt[a][q] = sum_c y[a][c]*Cm[c][q]
#pragma unroll
    for (int a = 0; a < 3; ++a)
#pragma unroll
      for (int q = 0; q < 3; ++q)
        vt[a][q] = y[a][0] * Cm[0][q] + y[a][1] * Cm[1][q] + y[a][2] * Cm[2][q];
#pragma unroll
    for (int p = 0; p < 3; ++p) {
      const int h = bh * 3 + p;
      if (h >= 64) continue;               // crop (uniform per block)
#pragma unroll
      for (int q = 0; q < 3; ++q) {
        const int ww = bw * 3 + q;
        if (ww >= 64) continue;            // crop
        const float o = Cm[0][p] * vt[0][q] + Cm[1][p] * vt[1][q] + Cm[2][p] * vt[2][q];
        __builtin_nontemporal_store(
            o, out + ((((size_t)ib * 64 + h) * 64 + ww) * 768 + wv * 64 + lane));
      }
    }
  }
}

// ---------------------------------------------------------------------------
extern "C" void kernel_launch(void* const* d_in, const int* in_sizes, int n_in,
                              void* d_out, int out_size, void* d_ws, size_t ws_size,
                              hipStream_t stream) {
  const float* f  = (const float*)d_in[0];
  const float* W1 = (const float*)d_in[1];
  const float* b1 = (const float*)d_in[2];
  float* out = (float*)d_out;

  if (ws_size >= W1H_BYTES && d_ws != nullptr) {
    unsigned short* W1h = (unsigned short*)d_ws;
    w1conv<<<dim3(72), dim3(256), 0, stream>>>(W1, W1h);
    fused_kernel<true><<<dim3(NBLK), dim3(768), 0, stream>>>(f, W1, W1h, b1, out);
  } else {
    fused_kernel<false><<<dim3(NBLK), dim3(768), 0, stream>>>(f, W1, nullptr, b1, out);
  }
}